// Round 2
// baseline (337.905 us; speedup 1.0000x reference)
//
#include <hip/hip_runtime.h>
#include <hip/hip_bf16.h>

typedef __bf16 bf16x8 __attribute__((ext_vector_type(8)));
typedef __bf16 bf16x4 __attribute__((ext_vector_type(4)));
typedef float  f32x4  __attribute__((ext_vector_type(4)));

#define K_DIM 1024
#define N_DIM 1024
// fallback tile
#define BM 128
#define BN 128
#define BK 64
// pipelined tile
#define BM2 256
#define BN2 256
#define BK2 32
#define PDEPTH 4
#define NT2 (K_DIM / BK2)

typedef unsigned int u32;
typedef u32 __attribute__((address_space(1))) u32_g;
typedef u32 __attribute__((address_space(3))) u32_s;

__device__ __forceinline__ void load16_lds(const void* g, void* s) {
    // async global->LDS, 16B per lane; LDS dest = wave-uniform base + lane*16
    __builtin_amdgcn_global_load_lds((u32_g*)g, (u32_s*)s, 16, 0, 0);
}

// ---------------- 1. per-block max|kernel| (no atomics, no memset) ----------------
__global__ void maxabs_kernel(const float* __restrict__ w, float* __restrict__ blockmax, int n4) {
    __shared__ float sm[4];
    int i = blockIdx.x * blockDim.x + threadIdx.x;
    int stride = gridDim.x * blockDim.x;
    float m = 0.f;
    for (; i < n4; i += stride) {
        float4 v = ((const float4*)w)[i];
        m = fmaxf(m, fmaxf(fmaxf(fabsf(v.x), fabsf(v.y)), fmaxf(fabsf(v.z), fabsf(v.w))));
    }
#pragma unroll
    for (int off = 32; off > 0; off >>= 1)
        m = fmaxf(m, __shfl_down(m, off, 64));
    int lane = threadIdx.x & 63, wave = threadIdx.x >> 6;
    if (lane == 0) sm[wave] = m;
    __syncthreads();
    if (threadIdx.x == 0)
        blockmax[blockIdx.x] = fmaxf(fmaxf(sm[0], sm[1]), fmaxf(sm[2], sm[3]));
}

// ---------------- 2. W_eff^T (N x K, bf16) = quant-dequant(kernel) + a@b ----------------
__global__ void build_w_kernel(const float* __restrict__ kern, const float* __restrict__ amat,
                               const float* __restrict__ bmat, const float* __restrict__ blockmax,
                               __bf16* __restrict__ wt) {
    __shared__ float smax;
    if (threadIdx.x < 64) {
        float m = 0.f;
#pragma unroll
        for (int j = 0; j < 4; ++j) m = fmaxf(m, blockmax[threadIdx.x + j * 64]);
#pragma unroll
        for (int off = 32; off > 0; off >>= 1)
            m = fmaxf(m, __shfl_down(m, off, 64));
        if (threadIdx.x == 0) smax = m;
    }
    __syncthreads();
    float scale = smax * (1.0f / 7.0f);

    int t = blockIdx.x * blockDim.x + threadIdx.x;   // 0 .. 1M-1
    int k = t & (K_DIM - 1);
    int n = t >> 10;
    float w = kern[k * N_DIM + n];
    float q = rintf(w / scale);                      // RNE == jnp.round
    q = fminf(fmaxf(q, -8.f), 7.f);
    float acc = q * scale;
#pragma unroll
    for (int r = 0; r < 16; ++r)
        acc += amat[k * 16 + r] * bmat[r * N_DIM + n];
    wt[(size_t)n * K_DIM + k] = (__bf16)acc;
}

// ---------------- 3. x fp32 -> bf16 ----------------
__global__ void cvt_x_kernel(const float4* __restrict__ x, bf16x8* __restrict__ xb, int n8) {
    int i = blockIdx.x * blockDim.x + threadIdx.x;
    if (i >= n8) return;
    float4 v0 = x[i * 2];
    float4 v1 = x[i * 2 + 1];
    bf16x8 o;
    o[0] = (__bf16)v0.x; o[1] = (__bf16)v0.y; o[2] = (__bf16)v0.z; o[3] = (__bf16)v0.w;
    o[4] = (__bf16)v1.x; o[5] = (__bf16)v1.y; o[6] = (__bf16)v1.z; o[7] = (__bf16)v1.w;
    xb[i] = o;
}

// ---------------- 4. phased GEMM: out[M,N] = A[M,K] * Wt[N,K]^T + bias ----------------
// 256x256 tile, BK=32, 8 waves (2M x 4N), 4-deep circular LDS pipeline.
// NEW vs prev round: 4 phases per K-tile (8-phase-template style). Each phase:
//   {ds_read quadrant frags; issue 1 staging gload_lds; s_barrier;
//    per-wave lgkmcnt(0); setprio(1); 8 MFMA; setprio(0); s_barrier}
// Reads are ISSUED before the barrier but WAITED after it, per wave — waves
// whose reads land first start MFMA while the LDS pipe serves the rest
// (staircase overlap; setprio favors MFMA-ready waves).
// vmcnt gate once per K-tile at end of phase 3: vmcnt(8) = tiles t+2,t+3 in
// flight, tile t+1 landed. Never drains to 0 in the main loop.
__global__ __launch_bounds__(512, 2)
void gemm256_kernel(const __bf16* __restrict__ xb, const __bf16* __restrict__ wt,
                    const float* __restrict__ bias, float* __restrict__ out) {
    __shared__ __attribute__((aligned(16))) __bf16 As[PDEPTH][BM2 * BK2];
    __shared__ __attribute__((aligned(16))) __bf16 Bs[PDEPTH][BN2 * BK2];

    const int tid  = threadIdx.x;
    const int lane = tid & 63;
    const int wave = tid >> 6;          // 0..7
    const int wr   = wave >> 2;         // 0..1 (M half)
    const int wc   = wave & 3;          // 0..3 (N quarter)
    const int l15  = lane & 15;
    const int l4   = lane >> 4;

    // XCD swizzle: 512 blocks; xcd = lb&7; ib = lb>>3; n_tile = ib&3;
    // m_panel = (ib>>2)*8 + xcd  -> all 4 N-tiles of an M-panel share one XCD.
    const int lb  = blockIdx.x;
    const int ib  = lb >> 3;
    const int bn0 = (ib & 3) * BN2;
    const int bm0 = (((ib >> 2) << 3) | (lb & 7)) * BM2;

    // staging geometry: one gload_lds = 16 rows x 64B; lane l -> row base+(l>>2),
    // physical chunk l&3; source pre-swizzled so LDS[row][pc] holds k-chunk pc^((row>>1)&3)
    const int srow = lane >> 2;                        // 0..15
    const int lc   = (lane & 3) ^ ((srow >> 1) & 3);   // swizzled source chunk

    const __bf16* xg = xb + (size_t)(bm0 + wave * 32 + srow) * K_DIM + lc * 8;
    const __bf16* wg = wt + (size_t)(bn0 + wave * 32 + srow) * K_DIM + lc * 8;
    __bf16* sa = &As[0][wave * 32 * BK2];
    __bf16* sb = &Bs[0][wave * 32 * BK2];

    // compute-read offset within a [row][BK2] tile (swizzled, 16B aligned)
    const int ro = l15 * BK2 + ((l4 ^ ((l15 >> 1) & 3)) << 3);

    f32x4 acc[8][4] = {};

#define STAGE_ALL(T) do {                                                  \
        const int b_ = (T) & (PDEPTH - 1); const int k_ = (T) * BK2;       \
        load16_lds(xg + k_,              sa + b_ * (BM2 * BK2));           \
        load16_lds(xg + 16 * K_DIM + k_, sa + b_ * (BM2 * BK2) + 16 * BK2);\
        load16_lds(wg + k_,              sb + b_ * (BN2 * BK2));           \
        load16_lds(wg + 16 * K_DIM + k_, sb + b_ * (BN2 * BK2) + 16 * BK2);\
    } while (0)

    STAGE_ALL(0); STAGE_ALL(1); STAGE_ALL(2);
    asm volatile("s_waitcnt vmcnt(8)" ::: "memory");   // tile 0 landed
    __builtin_amdgcn_s_barrier();

#pragma unroll 4
    for (int t = 0; t < NT2; ++t) {
        const int buf = t & (PDEPTH - 1);
        const int stb = (t + 3) & (PDEPTH - 1);
        const int k_  = (t + 3) * BK2;
        const bool st = (t + 3) < NT2;
        const __bf16* ap = (const __bf16*)As + buf * (BM2 * BK2) + wr * (128 * BK2) + ro;
        const __bf16* bp = (const __bf16*)Bs + buf * (BN2 * BK2) + wc * (64 * BK2) + ro;
        bf16x8 af[4], bv0[2], bv1[2];

        // ---- phase 0: read A(m0-3)+B(n0-1); stage A-half0; MFMA Q(m0-3, n0-1)
#pragma unroll
        for (int mt = 0; mt < 4; ++mt) af[mt] = *(const bf16x8*)(ap + mt * (16 * BK2));
#pragma unroll
        for (int nt = 0; nt < 2; ++nt) bv0[nt] = *(const bf16x8*)(bp + nt * (16 * BK2));
        if (st) load16_lds(xg + k_, sa + stb * (BM2 * BK2));
        __builtin_amdgcn_s_barrier();
        asm volatile("s_waitcnt lgkmcnt(0)");
        __builtin_amdgcn_s_setprio(1);
#pragma unroll
        for (int mt = 0; mt < 4; ++mt)
#pragma unroll
            for (int nt = 0; nt < 2; ++nt)
                acc[mt][nt] = __builtin_amdgcn_mfma_f32_16x16x32_bf16(
                    af[mt], bv0[nt], acc[mt][nt], 0, 0, 0);
        __builtin_amdgcn_s_setprio(0);
        __builtin_amdgcn_s_barrier();

        // ---- phase 1: read B(n2-3); stage A-half1; MFMA Q(m0-3, n2-3)
#pragma unroll
        for (int nt = 0; nt < 2; ++nt) bv1[nt] = *(const bf16x8*)(bp + (32 + nt * 16) * BK2);
        if (st) load16_lds(xg + 16 * K_DIM + k_, sa + stb * (BM2 * BK2) + 16 * BK2);
        __builtin_amdgcn_s_barrier();
        asm volatile("s_waitcnt lgkmcnt(0)");
        __builtin_amdgcn_s_setprio(1);
#pragma unroll
        for (int mt = 0; mt < 4; ++mt)
#pragma unroll
            for (int nt = 0; nt < 2; ++nt)
                acc[mt][2 + nt] = __builtin_amdgcn_mfma_f32_16x16x32_bf16(
                    af[mt], bv1[nt], acc[mt][2 + nt], 0, 0, 0);
        __builtin_amdgcn_s_setprio(0);
        __builtin_amdgcn_s_barrier();

        // ---- phase 2: read A(m4-7); stage B-half0; MFMA Q(m4-7, n0-1)
#pragma unroll
        for (int mt = 0; mt < 4; ++mt) af[mt] = *(const bf16x8*)(ap + (64 + mt * 16) * BK2);
        if (st) load16_lds(wg + k_, sb + stb * (BN2 * BK2));
        __builtin_amdgcn_s_barrier();
        asm volatile("s_waitcnt lgkmcnt(0)");
        __builtin_amdgcn_s_setprio(1);
#pragma unroll
        for (int mt = 0; mt < 4; ++mt)
#pragma unroll
            for (int nt = 0; nt < 2; ++nt)
                acc[4 + mt][nt] = __builtin_amdgcn_mfma_f32_16x16x32_bf16(
                    af[mt], bv0[nt], acc[4 + mt][nt], 0, 0, 0);
        __builtin_amdgcn_s_setprio(0);
        __builtin_amdgcn_s_barrier();

        // ---- phase 3: no reads; stage B-half1; MFMA Q(m4-7, n2-3); vmcnt gate
        if (st) load16_lds(wg + 16 * K_DIM + k_, sb + stb * (BN2 * BK2) + 16 * BK2);
        __builtin_amdgcn_s_barrier();
        __builtin_amdgcn_s_setprio(1);
#pragma unroll
        for (int mt = 0; mt < 4; ++mt)
#pragma unroll
            for (int nt = 0; nt < 2; ++nt)
                acc[4 + mt][2 + nt] = __builtin_amdgcn_mfma_f32_16x16x32_bf16(
                    af[mt], bv1[nt], acc[4 + mt][2 + nt], 0, 0, 0);
        __builtin_amdgcn_s_setprio(0);
        if (t < NT2 - 3)       asm volatile("s_waitcnt vmcnt(8)" ::: "memory");
        else if (t == NT2 - 3) asm volatile("s_waitcnt vmcnt(4)" ::: "memory");
        else if (t == NT2 - 2) asm volatile("s_waitcnt vmcnt(0)" ::: "memory");
        __builtin_amdgcn_s_barrier();
    }
#undef STAGE_ALL

    // ---- epilogue: C/D layout col = lane&15, row = (lane>>4)*4 + reg ----
#pragma unroll
    for (int nt = 0; nt < 4; ++nt) {
        int n = bn0 + wc * 64 + nt * 16 + l15;
        float bvs = bias[n];
#pragma unroll
        for (int mt = 0; mt < 8; ++mt) {
            int m = bm0 + wr * 128 + mt * 16 + l4 * 4;
            float* op = out + (size_t)m * N_DIM + n;
#pragma unroll
            for (int r = 0; r < 4; ++r)
                op[(size_t)r * N_DIM] = acc[mt][nt][r] + bvs;
        }
    }
}

// ---------------- 4b. fallback GEMM (fp32 A, reg-staged), 128x128 ----------------
__global__ __launch_bounds__(256, 4)
void gemm_fb_kernel(const float* __restrict__ x, const __bf16* __restrict__ wt,
                    const float* __restrict__ bias, float* __restrict__ out) {
    __shared__ __attribute__((aligned(16))) __bf16 As[BM * BK];
    __shared__ __attribute__((aligned(16))) __bf16 Bs[BN * BK];

    const int tid  = threadIdx.x;
    const int lane = tid & 63;
    const int wave = tid >> 6;
    const int wm = (wave >> 1) * 64;
    const int wn = (wave & 1) * 64;

    const int l = blockIdx.x;
    const int i = l >> 3;
    const int bn0 = (i & 7) * BN;
    const int bm0 = (((i >> 3) << 3) | (l & 7)) * BM;

    const int l15 = lane & 15;
    const int l4  = lane >> 4;

    f32x4 acc[4][4] = {};

    const int srow = lane >> 3;
    const int gch  = (lane & 7) ^ srow;

    for (int k0 = 0; k0 < K_DIM; k0 += BK) {
        __syncthreads();
#pragma unroll
        for (int j = 0; j < 4; ++j) {
            int r = j * 32 + wave * 8;
            const __bf16* g = wt + (size_t)(bn0 + r + srow) * K_DIM + k0 + gch * 8;
            load16_lds(g, &Bs[r * BK]);
        }
#pragma unroll
        for (int j = 0; j < 8; ++j) {
            int f  = j * 256 + tid;
            int r  = f >> 4;
            int c4 = f & 15;
            float4 v = *(const float4*)(x + (size_t)(bm0 + r) * K_DIM + k0 + c4 * 4);
            int p = (c4 >> 1) ^ (r & 7);
            bf16x4 o;
            o.x = (__bf16)v.x; o.y = (__bf16)v.y; o.z = (__bf16)v.z; o.w = (__bf16)v.w;
            *(bf16x4*)(&As[r * BK + p * 8 + (c4 & 1) * 4]) = o;
        }
        __syncthreads();

#pragma unroll
        for (int ks = 0; ks < 2; ++ks) {
            bf16x8 af[4], bfr[4];
#pragma unroll
            for (int mt = 0; mt < 4; ++mt) {
                int r = wm + mt * 16 + l15;
                int p = (ks * 4 + l4) ^ (r & 7);
                af[mt] = *(const bf16x8*)(&As[r * BK + p * 8]);
            }
#pragma unroll
            for (int nt = 0; nt < 4; ++nt) {
                int r = wn + nt * 16 + l15;
                int p = (ks * 4 + l4) ^ (r & 7);
                bfr[nt] = *(const bf16x8*)(&Bs[r * BK + p * 8]);
            }
#pragma unroll
            for (int mt = 0; mt < 4; ++mt)
#pragma unroll
                for (int nt = 0; nt < 4; ++nt)
                    acc[mt][nt] = __builtin_amdgcn_mfma_f32_16x16x32_bf16(
                        af[mt], bfr[nt], acc[mt][nt], 0, 0, 0);
        }
    }

#pragma unroll
    for (int nt = 0; nt < 4; ++nt) {
        int n = bn0 + wn + nt * 16 + l15;
        float bv = bias[n];
#pragma unroll
        for (int mt = 0; mt < 4; ++mt) {
            int m = bm0 + wm + mt * 16 + l4 * 4;
            float* op = out + (size_t)m * N_DIM + n;
#pragma unroll
            for (int r = 0; r < 4; ++r)
                op[(size_t)r * N_DIM] = acc[mt][nt][r] + bv;
        }
    }
}

extern "C" void kernel_launch(void* const* d_in, const int* in_sizes, int n_in,
                              void* d_out, int out_size, void* d_ws, size_t ws_size,
                              hipStream_t stream) {
    const float* x    = (const float*)d_in[0];
    const float* kern = (const float*)d_in[1];
    const float* bias = (const float*)d_in[2];
    const float* amat = (const float*)d_in[3];
    const float* bmat = (const float*)d_in[4];
    float* out = (float*)d_out;
    const int M = in_sizes[0] / K_DIM;   // 32768

    float* blockmax = (float*)d_ws;                          // 256 floats
    __bf16* wt = (__bf16*)((char*)d_ws + 4096);
    const size_t xb_off    = 4096 + (size_t)N_DIM * K_DIM * sizeof(__bf16);
    const size_t need_fast = xb_off + (size_t)M * K_DIM * sizeof(__bf16);

    maxabs_kernel<<<256, 256, 0, stream>>>(kern, blockmax, K_DIM * N_DIM / 4);
    build_w_kernel<<<K_DIM * N_DIM / 256, 256, 0, stream>>>(kern, amat, bmat, blockmax, wt);

    // fast path needs ws for xb and M divisible by 256*8 (panel-swizzle bijectivity)
    if (ws_size >= need_fast && (M % (BM2 * 8)) == 0) {
        __bf16* xbuf = (__bf16*)((char*)d_ws + xb_off);
        int n8 = M * K_DIM / 8;
        cvt_x_kernel<<<(n8 + 255) / 256, 256, 0, stream>>>((const float4*)x, (bf16x8*)xbuf, n8);
        gemm256_kernel<<<(M / BM2) * (N_DIM / BN2), 512, 0, stream>>>(xbuf, wt, bias, out);
    } else {
        gemm_fb_kernel<<<(M / BM) * (N_DIM / BN), 256, 0, stream>>>(x, wt, bias, out);
    }
}

// Round 3
// 317.207 us; speedup vs baseline: 1.0653x; 1.0653x over previous
//
#include <hip/hip_runtime.h>
#include <hip/hip_bf16.h>

typedef __bf16 bf16x8 __attribute__((ext_vector_type(8)));
typedef __bf16 bf16x4 __attribute__((ext_vector_type(4)));
typedef float  f32x4  __attribute__((ext_vector_type(4)));

#define K_DIM 1024
#define N_DIM 1024
// fallback tile
#define BM 128
#define BN 128
#define BK 64
// pipelined tile
#define BM2 256
#define BN2 256
#define BK2 32
#define NT2 (K_DIM / BK2)
#define AS_T (BM2 * BK2)
#define BS_T (BN2 * BK2)

typedef unsigned int u32;
typedef u32 __attribute__((address_space(1))) u32_g;
typedef u32 __attribute__((address_space(3))) u32_s;

__device__ __forceinline__ void load16_lds(const void* g, void* s) {
    // async global->LDS, 16B per lane; LDS dest = wave-uniform base + lane*16
    __builtin_amdgcn_global_load_lds((u32_g*)g, (u32_s*)s, 16, 0, 0);
}

// ---------------- 1. per-block max|kernel| (no atomics, no memset) ----------------
__global__ void maxabs_kernel(const float* __restrict__ w, float* __restrict__ blockmax, int n4) {
    __shared__ float sm[4];
    int i = blockIdx.x * blockDim.x + threadIdx.x;
    int stride = gridDim.x * blockDim.x;
    float m = 0.f;
    for (; i < n4; i += stride) {
        float4 v = ((const float4*)w)[i];
        m = fmaxf(m, fmaxf(fmaxf(fabsf(v.x), fabsf(v.y)), fmaxf(fabsf(v.z), fabsf(v.w))));
    }
#pragma unroll
    for (int off = 32; off > 0; off >>= 1)
        m = fmaxf(m, __shfl_down(m, off, 64));
    int lane = threadIdx.x & 63, wave = threadIdx.x >> 6;
    if (lane == 0) sm[wave] = m;
    __syncthreads();
    if (threadIdx.x == 0)
        blockmax[blockIdx.x] = fmaxf(fmaxf(sm[0], sm[1]), fmaxf(sm[2], sm[3]));
}

// ---------------- 2. W_eff^T (N x K, bf16) = quant-dequant(kernel) + a@b ----------------
__global__ void build_w_kernel(const float* __restrict__ kern, const float* __restrict__ amat,
                               const float* __restrict__ bmat, const float* __restrict__ blockmax,
                               __bf16* __restrict__ wt) {
    __shared__ float smax;
    if (threadIdx.x < 64) {
        float m = 0.f;
#pragma unroll
        for (int j = 0; j < 4; ++j) m = fmaxf(m, blockmax[threadIdx.x + j * 64]);
#pragma unroll
        for (int off = 32; off > 0; off >>= 1)
            m = fmaxf(m, __shfl_down(m, off, 64));
        if (threadIdx.x == 0) smax = m;
    }
    __syncthreads();
    float scale = smax * (1.0f / 7.0f);

    int t = blockIdx.x * blockDim.x + threadIdx.x;   // 0 .. 1M-1
    int k = t & (K_DIM - 1);
    int n = t >> 10;
    float w = kern[k * N_DIM + n];
    float q = rintf(w / scale);                      // RNE == jnp.round
    q = fminf(fmaxf(q, -8.f), 7.f);
    float acc = q * scale;
#pragma unroll
    for (int r = 0; r < 16; ++r)
        acc += amat[k * 16 + r] * bmat[r * N_DIM + n];
    wt[(size_t)n * K_DIM + k] = (__bf16)acc;
}

// ---------------- 3. x fp32 -> bf16 ----------------
__global__ void cvt_x_kernel(const float4* __restrict__ x, bf16x8* __restrict__ xb, int n8) {
    int i = blockIdx.x * blockDim.x + threadIdx.x;
    if (i >= n8) return;
    float4 v0 = x[i * 2];
    float4 v1 = x[i * 2 + 1];
    bf16x8 o;
    o[0] = (__bf16)v0.x; o[1] = (__bf16)v0.y; o[2] = (__bf16)v0.z; o[3] = (__bf16)v0.w;
    o[4] = (__bf16)v1.x; o[5] = (__bf16)v1.y; o[6] = (__bf16)v1.z; o[7] = (__bf16)v1.w;
    xb[i] = o;
}

// ---------------- 4. GEMM: out[M,N] = A[M,K] * Wt[N,K]^T + bias ----------------
// 256x256 tile, BK=32, 8 waves (2M x 4N), 4-deep ring, 2 K-tiles/iter.
// Per K-tile "half": 12 ds_reads issued up-front, then three MFMA clusters
// gated by PARTIAL lgkmcnt waits (6 -> 8 MFMA -> 2 -> 8 MFMA -> 0 -> 16 MFMA)
// so each wave's trailing reads complete UNDER its own MFMAs and the LDS pipe
// feeds waves in a staircase instead of burst-alternation. Stage gloads
// interleave between clusters. ONE counted vmcnt(8)+barrier per K-tile.
// Hazards verified: every stage targets a buffer whose readers drained before
// the preceding barrier; OOB stage tiles wrap (&31) into provably-free slots
// so gate counts stay uniform (never vmcnt(0) in the loop).
__global__ __launch_bounds__(512, 2)
void gemm256_kernel(const __bf16* __restrict__ xb, const __bf16* __restrict__ wt,
                    const float* __restrict__ bias, float* __restrict__ out) {
    __shared__ __attribute__((aligned(16))) __bf16 As[4][AS_T];
    __shared__ __attribute__((aligned(16))) __bf16 Bs[4][BS_T];

    const int tid  = threadIdx.x;
    const int lane = tid & 63;
    const int wave = tid >> 6;          // 0..7
    const int wr   = wave >> 2;         // 0..1 (M half)
    const int wc   = wave & 3;          // 0..3 (N quarter)
    const int l15  = lane & 15;
    const int l4   = lane >> 4;

    // XCD swizzle: 512 blocks; xcd = lb&7; ib = lb>>3; n_tile = ib&3;
    // m_panel = (ib>>2)*8 + xcd  -> all 4 N-tiles of an M-panel share one XCD.
    const int lb  = blockIdx.x;
    const int ib  = lb >> 3;
    const int bn0 = (ib & 3) * BN2;
    const int bm0 = (((ib >> 2) << 3) | (lb & 7)) * BM2;

    // staging geometry: one gload_lds = 16 rows x 64B; lane l -> row base+(l>>2),
    // physical chunk l&3; source pre-swizzled so LDS[row][pc] holds k-chunk pc^((row>>1)&3)
    const int srow = lane >> 2;                        // 0..15
    const int lc   = (lane & 3) ^ ((srow >> 1) & 3);   // swizzled source chunk

    const __bf16* xg = xb + (size_t)(bm0 + wave * 32 + srow) * K_DIM + lc * 8;
    const __bf16* wg = wt + (size_t)(bn0 + wave * 32 + srow) * K_DIM + lc * 8;
    __bf16* sa = &As[0][wave * 32 * BK2];
    __bf16* sb = &Bs[0][wave * 32 * BK2];

    // compute-read offset within a [row][BK2] tile (swizzled, 16B aligned)
    const int ro = l15 * BK2 + ((l4 ^ ((l15 >> 1) & 3)) << 3);

    f32x4 acc[8][4] = {};

#define STAGE_A(T) do { int b_ = (T) & 3; int k_ = ((T) & 31) * BK2;        \
        load16_lds(xg + k_,              sa + b_ * AS_T);                   \
        load16_lds(xg + 16 * K_DIM + k_, sa + b_ * AS_T + 16 * BK2); } while (0)
#define STAGE_B(T) do { int b_ = (T) & 3; int k_ = ((T) & 31) * BK2;        \
        load16_lds(wg + k_,              sb + b_ * BS_T);                   \
        load16_lds(wg + 16 * K_DIM + k_, sb + b_ * BS_T + 16 * BK2); } while (0)

// One K-tile: buf = LDS slot, ST = tile to stage (wrapped).
// Read order (12): af0-3, bv0-1, af4-7, bv2-3  -> partial waits 6 / 2 / 0.
#define HALF(BUFI, ST) do {                                                  \
        const int buf_ = (BUFI);                                             \
        const __bf16* ap = (const __bf16*)As + buf_ * AS_T + wr * (128 * BK2) + ro; \
        const __bf16* bp = (const __bf16*)Bs + buf_ * BS_T + wc * (64 * BK2) + ro;  \
        bf16x8 af[8], bv[4];                                                 \
        af[0] = *(const bf16x8*)(ap + 0 * (16 * BK2));                       \
        af[1] = *(const bf16x8*)(ap + 1 * (16 * BK2));                       \
        af[2] = *(const bf16x8*)(ap + 2 * (16 * BK2));                       \
        af[3] = *(const bf16x8*)(ap + 3 * (16 * BK2));                       \
        bv[0] = *(const bf16x8*)(bp + 0 * (16 * BK2));                       \
        bv[1] = *(const bf16x8*)(bp + 1 * (16 * BK2));                       \
        af[4] = *(const bf16x8*)(ap + 4 * (16 * BK2));                       \
        af[5] = *(const bf16x8*)(ap + 5 * (16 * BK2));                       \
        af[6] = *(const bf16x8*)(ap + 6 * (16 * BK2));                       \
        af[7] = *(const bf16x8*)(ap + 7 * (16 * BK2));                       \
        bv[2] = *(const bf16x8*)(bp + 2 * (16 * BK2));                       \
        bv[3] = *(const bf16x8*)(bp + 3 * (16 * BK2));                       \
        STAGE_A(ST);                                                         \
        asm volatile("s_waitcnt lgkmcnt(6)" ::: "memory");                   \
        __builtin_amdgcn_sched_barrier(0);                                   \
        __builtin_amdgcn_s_setprio(1);                                       \
        _Pragma("unroll") for (int mt = 0; mt < 4; ++mt)                     \
        _Pragma("unroll") for (int nt = 0; nt < 2; ++nt)                     \
            acc[mt][nt] = __builtin_amdgcn_mfma_f32_16x16x32_bf16(           \
                af[mt], bv[nt], acc[mt][nt], 0, 0, 0);                       \
        asm volatile("s_waitcnt lgkmcnt(2)" ::: "memory");                   \
        __builtin_amdgcn_sched_barrier(0);                                   \
        _Pragma("unroll") for (int mt = 4; mt < 8; ++mt)                     \
        _Pragma("unroll") for (int nt = 0; nt < 2; ++nt)                     \
            acc[mt][nt] = __builtin_amdgcn_mfma_f32_16x16x32_bf16(           \
                af[mt], bv[nt], acc[mt][nt], 0, 0, 0);                       \
        STAGE_B(ST);                                                         \
        asm volatile("s_waitcnt lgkmcnt(0)" ::: "memory");                   \
        __builtin_amdgcn_sched_barrier(0);                                   \
        _Pragma("unroll") for (int mt = 0; mt < 8; ++mt)                     \
        _Pragma("unroll") for (int nt = 2; nt < 4; ++nt)                     \
            acc[mt][nt] = __builtin_amdgcn_mfma_f32_16x16x32_bf16(           \
                af[mt], bv[nt], acc[mt][nt], 0, 0, 0);                       \
        __builtin_amdgcn_s_setprio(0);                                       \
        asm volatile("s_waitcnt vmcnt(8)" ::: "memory");                     \
        __builtin_amdgcn_s_barrier();                                        \
    } while (0)

    // prologue: stage tiles 0,1,2 (12 loads); vmcnt(8) -> tile 0 landed
    STAGE_A(0); STAGE_B(0);
    STAGE_A(1); STAGE_B(1);
    STAGE_A(2); STAGE_B(2);
    asm volatile("s_waitcnt vmcnt(8)" ::: "memory");
    __builtin_amdgcn_s_barrier();

#pragma unroll 1
    for (int u = 0; u < NT2 / 2; ++u) {
        const int t0 = 2 * u;
        // mid gate vmcnt(8): tile t0+1 landed; end gate vmcnt(8): tile t0+2 landed.
        HALF(t0 & 3, t0 + 3);
        HALF((t0 + 1) & 3, t0 + 4);
    }
#undef HALF
#undef STAGE_A
#undef STAGE_B

    // ---- epilogue: C/D layout col = lane&15, row = (lane>>4)*4 + reg ----
#pragma unroll
    for (int nt = 0; nt < 4; ++nt) {
        int n = bn0 + wc * 64 + nt * 16 + l15;
        float bvs = bias[n];
#pragma unroll
        for (int mt = 0; mt < 8; ++mt) {
            int m = bm0 + wr * 128 + mt * 16 + l4 * 4;
            float* op = out + (size_t)m * N_DIM + n;
#pragma unroll
            for (int r = 0; r < 4; ++r)
                op[(size_t)r * N_DIM] = acc[mt][nt][r] + bvs;
        }
    }
}

// ---------------- 4b. fallback GEMM (fp32 A, reg-staged), 128x128 ----------------
__global__ __launch_bounds__(256, 4)
void gemm_fb_kernel(const float* __restrict__ x, const __bf16* __restrict__ wt,
                    const float* __restrict__ bias, float* __restrict__ out) {
    __shared__ __attribute__((aligned(16))) __bf16 As[BM * BK];
    __shared__ __attribute__((aligned(16))) __bf16 Bs[BN * BK];

    const int tid  = threadIdx.x;
    const int lane = tid & 63;
    const int wave = tid >> 6;
    const int wm = (wave >> 1) * 64;
    const int wn = (wave & 1) * 64;

    const int l = blockIdx.x;
    const int i = l >> 3;
    const int bn0 = (i & 7) * BN;
    const int bm0 = (((i >> 3) << 3) | (l & 7)) * BM;

    const int l15 = lane & 15;
    const int l4  = lane >> 4;

    f32x4 acc[4][4] = {};

    const int srow = lane >> 3;
    const int gch  = (lane & 7) ^ srow;

    for (int k0 = 0; k0 < K_DIM; k0 += BK) {
        __syncthreads();
#pragma unroll
        for (int j = 0; j < 4; ++j) {
            int r = j * 32 + wave * 8;
            const __bf16* g = wt + (size_t)(bn0 + r + srow) * K_DIM + k0 + gch * 8;
            load16_lds(g, &Bs[r * BK]);
        }
#pragma unroll
        for (int j = 0; j < 8; ++j) {
            int f  = j * 256 + tid;
            int r  = f >> 4;
            int c4 = f & 15;
            float4 v = *(const float4*)(x + (size_t)(bm0 + r) * K_DIM + k0 + c4 * 4);
            int p = (c4 >> 1) ^ (r & 7);
            bf16x4 o;
            o.x = (__bf16)v.x; o.y = (__bf16)v.y; o.z = (__bf16)v.z; o.w = (__bf16)v.w;
            *(bf16x4*)(&As[r * BK + p * 8 + (c4 & 1) * 4]) = o;
        }
        __syncthreads();

#pragma unroll
        for (int ks = 0; ks < 2; ++ks) {
            bf16x8 af[4], bfr[4];
#pragma unroll
            for (int mt = 0; mt < 4; ++mt) {
                int r = wm + mt * 16 + l15;
                int p = (ks * 4 + l4) ^ (r & 7);
                af[mt] = *(const bf16x8*)(&As[r * BK + p * 8]);
            }
#pragma unroll
            for (int nt = 0; nt < 4; ++nt) {
                int r = wn + nt * 16 + l15;
                int p = (ks * 4 + l4) ^ (r & 7);
                bfr[nt] = *(const bf16x8*)(&Bs[r * BK + p * 8]);
            }
#pragma unroll
            for (int mt = 0; mt < 4; ++mt)
#pragma unroll
                for (int nt = 0; nt < 4; ++nt)
                    acc[mt][nt] = __builtin_amdgcn_mfma_f32_16x16x32_bf16(
                        af[mt], bfr[nt], acc[mt][nt], 0, 0, 0);
        }
    }

#pragma unroll
    for (int nt = 0; nt < 4; ++nt) {
        int n = bn0 + wn + nt * 16 + l15;
        float bv = bias[n];
#pragma unroll
        for (int mt = 0; mt < 4; ++mt) {
            int m = bm0 + wm + mt * 16 + l4 * 4;
            float* op = out + (size_t)m * N_DIM + n;
#pragma unroll
            for (int r = 0; r < 4; ++r)
                op[(size_t)r * N_DIM] = acc[mt][nt][r] + bv;
        }
    }
}

extern "C" void kernel_launch(void* const* d_in, const int* in_sizes, int n_in,
                              void* d_out, int out_size, void* d_ws, size_t ws_size,
                              hipStream_t stream) {
    const float* x    = (const float*)d_in[0];
    const float* kern = (const float*)d_in[1];
    const float* bias = (const float*)d_in[2];
    const float* amat = (const float*)d_in[3];
    const float* bmat = (const float*)d_in[4];
    float* out = (float*)d_out;
    const int M = in_sizes[0] / K_DIM;   // 32768

    float* blockmax = (float*)d_ws;                          // 256 floats
    __bf16* wt = (__bf16*)((char*)d_ws + 4096);
    const size_t xb_off    = 4096 + (size_t)N_DIM * K_DIM * sizeof(__bf16);
    const size_t need_fast = xb_off + (size_t)M * K_DIM * sizeof(__bf16);

    maxabs_kernel<<<256, 256, 0, stream>>>(kern, blockmax, K_DIM * N_DIM / 4);
    build_w_kernel<<<K_DIM * N_DIM / 256, 256, 0, stream>>>(kern, amat, bmat, blockmax, wt);

    // fast path needs ws for xb and M divisible by 256*8 (panel-swizzle bijectivity)
    if (ws_size >= need_fast && (M % (BM2 * 8)) == 0) {
        __bf16* xbuf = (__bf16*)((char*)d_ws + xb_off);
        int n8 = M * K_DIM / 8;
        cvt_x_kernel<<<(n8 + 255) / 256, 256, 0, stream>>>((const float4*)x, (bf16x8*)xbuf, n8);
        gemm256_kernel<<<(M / BM2) * (N_DIM / BN2), 512, 0, stream>>>(xbuf, wt, bias, out);
    } else {
        gemm_fb_kernel<<<(M / BM) * (N_DIM / BN), 256, 0, stream>>>(x, wt, bias, out);
    }
}

// Round 4
// 309.171 us; speedup vs baseline: 1.0929x; 1.0260x over previous
//
#include <hip/hip_runtime.h>
#include <hip/hip_bf16.h>

typedef __bf16 bf16x8 __attribute__((ext_vector_type(8)));
typedef __bf16 bf16x4 __attribute__((ext_vector_type(4)));
typedef float  f32x4  __attribute__((ext_vector_type(4)));

#define K_DIM 1024
#define N_DIM 1024
// fallback tile
#define BM 128
#define BN 128
#define BK 64
// pipelined tile
#define BM2 256
#define BN2 256
#define BK2 32
#define NT2 (K_DIM / BK2)
#define AS_T (BM2 * BK2)
#define BS_T (BN2 * BK2)

typedef unsigned int u32;
typedef u32 __attribute__((address_space(1))) u32_g;
typedef u32 __attribute__((address_space(3))) u32_s;

__device__ __forceinline__ void load16_lds(const void* g, void* s) {
    // async global->LDS, 16B per lane; LDS dest = wave-uniform base + lane*16
    __builtin_amdgcn_global_load_lds((u32_g*)g, (u32_s*)s, 16, 0, 0);
}

// ---------------- 1. per-block max|kernel| (no atomics, no memset) ----------------
__global__ void maxabs_kernel(const float* __restrict__ w, float* __restrict__ blockmax, int n4) {
    __shared__ float sm[4];
    int i = blockIdx.x * blockDim.x + threadIdx.x;
    int stride = gridDim.x * blockDim.x;
    float m = 0.f;
    for (; i < n4; i += stride) {
        float4 v = ((const float4*)w)[i];
        m = fmaxf(m, fmaxf(fmaxf(fabsf(v.x), fabsf(v.y)), fmaxf(fabsf(v.z), fabsf(v.w))));
    }
#pragma unroll
    for (int off = 32; off > 0; off >>= 1)
        m = fmaxf(m, __shfl_down(m, off, 64));
    int lane = threadIdx.x & 63, wave = threadIdx.x >> 6;
    if (lane == 0) sm[wave] = m;
    __syncthreads();
    if (threadIdx.x == 0)
        blockmax[blockIdx.x] = fmaxf(fmaxf(sm[0], sm[1]), fmaxf(sm[2], sm[3]));
}

// ---------------- 2. W_eff^T (N x K, bf16) = quant-dequant(kernel) + a@b ----------------
__global__ void build_w_kernel(const float* __restrict__ kern, const float* __restrict__ amat,
                               const float* __restrict__ bmat, const float* __restrict__ blockmax,
                               __bf16* __restrict__ wt) {
    __shared__ float smax;
    if (threadIdx.x < 64) {
        float m = 0.f;
#pragma unroll
        for (int j = 0; j < 4; ++j) m = fmaxf(m, blockmax[threadIdx.x + j * 64]);
#pragma unroll
        for (int off = 32; off > 0; off >>= 1)
            m = fmaxf(m, __shfl_down(m, off, 64));
        if (threadIdx.x == 0) smax = m;
    }
    __syncthreads();
    float scale = smax * (1.0f / 7.0f);

    int t = blockIdx.x * blockDim.x + threadIdx.x;   // 0 .. 1M-1
    int k = t & (K_DIM - 1);
    int n = t >> 10;
    float w = kern[k * N_DIM + n];
    float q = rintf(w / scale);                      // RNE == jnp.round
    q = fminf(fmaxf(q, -8.f), 7.f);
    float acc = q * scale;
#pragma unroll
    for (int r = 0; r < 16; ++r)
        acc += amat[k * 16 + r] * bmat[r * N_DIM + n];
    wt[(size_t)n * K_DIM + k] = (__bf16)acc;
}

// ---------------- 3. GEMM: out[M,N] = x[M,K](fp32) * Wt[N,K]^T + bias ----------------
// 256x256 tile, BK=32, 8 waves (2M x 4N). Round-3 schedule (partial-lgkm
// staircase: 6 -> 8 MFMA -> 2 -> 8 MFMA -> 0 -> 16 MFMA, one barrier/K-tile)
// with the fp32->bf16 conversion FUSED into A-staging (kills the cvt_x pass):
//   A: 4 coalesced global_load_dwordx4 (fp32 x) -> regs (issued mid-iter t for
//      tile t+2), cvt, 4 ds_write_b64 at iter t+1 into double-buffered As.
//      Write swizzle == read swizzle (pc = chunk ^ ((row>>1)&3), j-invariant).
//   B: unchanged 4-deep global_load_lds ring (pre-swizzled source).
// vmcnt ledger (FIFO), steady state per iter t:
//   enter {B(t+1),B(t+2)?,A(t+1)}; top: +B(t+3);
//   mid: vmcnt(2) = wait A(t+1) regs (drains all older B; >1 iter slack);
//        WRITEA(t+1); issue A(t+2); lgkm(0); cluster3; barrier.
// Never drains vmcnt to 0 in the loop. WAR safe: As write slot (t+1)&1 readers
// (tile t-1) drained at prev barrier; Bs write slot (t+3)&3 readers (tile t-1)
// likewise.
__global__ __launch_bounds__(512, 2)
void gemm256_kernel(const float* __restrict__ x, const __bf16* __restrict__ wt,
                    const float* __restrict__ bias, float* __restrict__ out) {
    __shared__ __attribute__((aligned(16))) __bf16 As[2][AS_T];
    __shared__ __attribute__((aligned(16))) __bf16 Bs[4][BS_T];

    const int tid  = threadIdx.x;
    const int lane = tid & 63;
    const int wave = tid >> 6;          // 0..7
    const int wr   = wave >> 2;         // 0..1 (M half)
    const int wc   = wave & 3;          // 0..3 (N quarter)
    const int l15  = lane & 15;
    const int l4   = lane >> 4;

    // XCD swizzle: 512 blocks; xcd = lb&7; ib = lb>>3; n_tile = ib&3;
    // m_panel = (ib>>2)*8 + xcd  -> all 4 N-tiles of an M-panel share one XCD.
    const int lb  = blockIdx.x;
    const int ib  = lb >> 3;
    const int bn0 = (ib & 3) * BN2;
    const int bm0 = (((ib >> 2) << 3) | (lb & 7)) * BM2;

    // ---- B staging geometry (gload_lds, pre-swizzled source) ----
    const int srow = lane >> 2;                        // 0..15
    const int lc   = (lane & 3) ^ ((srow >> 1) & 3);   // swizzled source chunk
    const __bf16* wg = wt + (size_t)(bn0 + wave * 32 + srow) * K_DIM + lc * 8;
    __bf16* sb = &Bs[0][wave * 32 * BK2];

    // ---- A staging geometry (reg-staged fp32 -> bf16) ----
    // load j covers rows j*64 + (tid>>3); lane-contiguous float4 -> coalesced.
    const int r0  = tid >> 3;                          // 0..63
    const int c4  = tid & 7;                           // float4 chunk in row
    const int apc = (c4 >> 1) ^ ((r0 >> 1) & 3);       // physical chunk (j-invariant)
    const int awr = r0 * BK2 + apc * 8 + (c4 & 1) * 4; // bf16 elem offset in slot
    const float* ag = x + (size_t)(bm0 + r0) * K_DIM + c4 * 4;

    // compute-read offset within a [row][BK2] tile (swizzled, 16B aligned)
    const int ro = l15 * BK2 + ((l4 ^ ((l15 >> 1) & 3)) << 3);

    f32x4 acc[8][4] = {};
    float4 av0, av1, av2, av3;

#define STAGE_B(T) do { int b_ = (T) & 3; int k_ = ((T) & 31) * BK2;        \
        load16_lds(wg + k_,              sb + b_ * BS_T);                   \
        load16_lds(wg + 16 * K_DIM + k_, sb + b_ * BS_T + 16 * BK2); } while (0)

#define LOADA(T) do { const float* p_ = ag + ((T) & 31) * BK2;              \
        av0 = *(const float4*)(p_);                                         \
        av1 = *(const float4*)(p_ +  64 * K_DIM);                           \
        av2 = *(const float4*)(p_ + 128 * K_DIM);                           \
        av3 = *(const float4*)(p_ + 192 * K_DIM); } while (0)

#define WRITEA(T) do { __bf16* d_ = &As[(T) & 1][awr];                      \
        bf16x4 o0, o1, o2, o3;                                              \
        o0.x=(__bf16)av0.x; o0.y=(__bf16)av0.y; o0.z=(__bf16)av0.z; o0.w=(__bf16)av0.w; \
        o1.x=(__bf16)av1.x; o1.y=(__bf16)av1.y; o1.z=(__bf16)av1.z; o1.w=(__bf16)av1.w; \
        o2.x=(__bf16)av2.x; o2.y=(__bf16)av2.y; o2.z=(__bf16)av2.z; o2.w=(__bf16)av2.w; \
        o3.x=(__bf16)av3.x; o3.y=(__bf16)av3.y; o3.z=(__bf16)av3.z; o3.w=(__bf16)av3.w; \
        *(bf16x4*)(d_)        = o0;  *(bf16x4*)(d_ + 2048) = o1;            \
        *(bf16x4*)(d_ + 4096) = o2;  *(bf16x4*)(d_ + 6144) = o3; } while (0)

    // ---- prologue ----
    LOADA(0);                              // FIFO: A(0)4
    STAGE_B(0); STAGE_B(1); STAGE_B(2);    // +B(0)2 B(1)2 B(2)2 -> 10
    asm volatile("s_waitcnt vmcnt(6)" ::: "memory");   // A(0) done
    __builtin_amdgcn_sched_barrier(0);
    WRITEA(0);
    LOADA(1);                              // FIFO: B0,B1,B2,A(1) -> 10
    asm volatile("s_waitcnt vmcnt(8)" ::: "memory");   // B(0) done
    asm volatile("s_waitcnt lgkmcnt(0)" ::: "memory"); // As[0] writes done
    __builtin_amdgcn_s_barrier();

#define ITER(t) do {                                                         \
        const int buf_ = (t) & 1; const int bbuf_ = (t) & 3;                 \
        const __bf16* ap = (const __bf16*)As + buf_ * AS_T + wr * (128 * BK2) + ro; \
        const __bf16* bp = (const __bf16*)Bs + bbuf_ * BS_T + wc * (64 * BK2) + ro; \
        bf16x8 af[8], bv[4];                                                 \
        af[0] = *(const bf16x8*)(ap + 0 * (16 * BK2));                       \
        af[1] = *(const bf16x8*)(ap + 1 * (16 * BK2));                       \
        af[2] = *(const bf16x8*)(ap + 2 * (16 * BK2));                       \
        af[3] = *(const bf16x8*)(ap + 3 * (16 * BK2));                       \
        bv[0] = *(const bf16x8*)(bp + 0 * (16 * BK2));                       \
        bv[1] = *(const bf16x8*)(bp + 1 * (16 * BK2));                       \
        af[4] = *(const bf16x8*)(ap + 4 * (16 * BK2));                       \
        af[5] = *(const bf16x8*)(ap + 5 * (16 * BK2));                       \
        af[6] = *(const bf16x8*)(ap + 6 * (16 * BK2));                       \
        af[7] = *(const bf16x8*)(ap + 7 * (16 * BK2));                       \
        bv[2] = *(const bf16x8*)(bp + 2 * (16 * BK2));                       \
        bv[3] = *(const bf16x8*)(bp + 3 * (16 * BK2));                       \
        STAGE_B((t) + 3);                                                    \
        asm volatile("s_waitcnt lgkmcnt(6)" ::: "memory");                   \
        __builtin_amdgcn_sched_barrier(0);                                   \
        __builtin_amdgcn_s_setprio(1);                                       \
        _Pragma("unroll") for (int mt = 0; mt < 4; ++mt)                     \
        _Pragma("unroll") for (int nt = 0; nt < 2; ++nt)                     \
            acc[mt][nt] = __builtin_amdgcn_mfma_f32_16x16x32_bf16(           \
                af[mt], bv[nt], acc[mt][nt], 0, 0, 0);                       \
        asm volatile("s_waitcnt lgkmcnt(2)" ::: "memory");                   \
        __builtin_amdgcn_sched_barrier(0);                                   \
        _Pragma("unroll") for (int mt = 4; mt < 8; ++mt)                     \
        _Pragma("unroll") for (int nt = 0; nt < 2; ++nt)                     \
            acc[mt][nt] = __builtin_amdgcn_mfma_f32_16x16x32_bf16(           \
                af[mt], bv[nt], acc[mt][nt], 0, 0, 0);                       \
        asm volatile("s_waitcnt vmcnt(2)" ::: "memory");                     \
        __builtin_amdgcn_sched_barrier(0);                                   \
        WRITEA((t) + 1);                                                     \
        LOADA((t) + 2);                                                      \
        asm volatile("s_waitcnt lgkmcnt(0)" ::: "memory");                   \
        __builtin_amdgcn_sched_barrier(0);                                   \
        _Pragma("unroll") for (int mt = 0; mt < 8; ++mt)                     \
        _Pragma("unroll") for (int nt = 2; nt < 4; ++nt)                     \
            acc[mt][nt] = __builtin_amdgcn_mfma_f32_16x16x32_bf16(           \
                af[mt], bv[nt], acc[mt][nt], 0, 0, 0);                       \
        __builtin_amdgcn_s_setprio(0);                                       \
        __builtin_amdgcn_s_barrier();                                        \
    } while (0)

#pragma unroll 4
    for (int t = 0; t < NT2; ++t) ITER(t);
#undef ITER
#undef STAGE_B
#undef LOADA
#undef WRITEA

    // ---- epilogue: C/D layout col = lane&15, row = (lane>>4)*4 + reg ----
#pragma unroll
    for (int nt = 0; nt < 4; ++nt) {
        int n = bn0 + wc * 64 + nt * 16 + l15;
        float bvs = bias[n];
#pragma unroll
        for (int mt = 0; mt < 8; ++mt) {
            int m = bm0 + wr * 128 + mt * 16 + l4 * 4;
            float* op = out + (size_t)m * N_DIM + n;
#pragma unroll
            for (int r = 0; r < 4; ++r)
                op[(size_t)r * N_DIM] = acc[mt][nt][r] + bvs;
        }
    }
}

// ---------------- 3b. fallback GEMM (fp32 A, reg-staged), 128x128 ----------------
__global__ __launch_bounds__(256, 4)
void gemm_fb_kernel(const float* __restrict__ x, const __bf16* __restrict__ wt,
                    const float* __restrict__ bias, float* __restrict__ out) {
    __shared__ __attribute__((aligned(16))) __bf16 As[BM * BK];
    __shared__ __attribute__((aligned(16))) __bf16 Bs[BN * BK];

    const int tid  = threadIdx.x;
    const int lane = tid & 63;
    const int wave = tid >> 6;
    const int wm = (wave >> 1) * 64;
    const int wn = (wave & 1) * 64;

    const int l = blockIdx.x;
    const int i = l >> 3;
    const int bn0 = (i & 7) * BN;
    const int bm0 = (((i >> 3) << 3) | (l & 7)) * BM;

    const int l15 = lane & 15;
    const int l4  = lane >> 4;

    f32x4 acc[4][4] = {};

    const int srow = lane >> 3;
    const int gch  = (lane & 7) ^ srow;

    for (int k0 = 0; k0 < K_DIM; k0 += BK) {
        __syncthreads();
#pragma unroll
        for (int j = 0; j < 4; ++j) {
            int r = j * 32 + wave * 8;
            const __bf16* g = wt + (size_t)(bn0 + r + srow) * K_DIM + k0 + gch * 8;
            load16_lds(g, &Bs[r * BK]);
        }
#pragma unroll
        for (int j = 0; j < 8; ++j) {
            int f  = j * 256 + tid;
            int r  = f >> 4;
            int c4 = f & 15;
            float4 v = *(const float4*)(x + (size_t)(bm0 + r) * K_DIM + k0 + c4 * 4);
            int p = (c4 >> 1) ^ (r & 7);
            bf16x4 o;
            o.x = (__bf16)v.x; o.y = (__bf16)v.y; o.z = (__bf16)v.z; o.w = (__bf16)v.w;
            *(bf16x4*)(&As[r * BK + p * 8 + (c4 & 1) * 4]) = o;
        }
        __syncthreads();

#pragma unroll
        for (int ks = 0; ks < 2; ++ks) {
            bf16x8 af[4], bfr[4];
#pragma unroll
            for (int mt = 0; mt < 4; ++mt) {
                int r = wm + mt * 16 + l15;
                int p = (ks * 4 + l4) ^ (r & 7);
                af[mt] = *(const bf16x8*)(&As[r * BK + p * 8]);
            }
#pragma unroll
            for (int nt = 0; nt < 4; ++nt) {
                int r = wn + nt * 16 + l15;
                int p = (ks * 4 + l4) ^ (r & 7);
                bfr[nt] = *(const bf16x8*)(&Bs[r * BK + p * 8]);
            }
#pragma unroll
            for (int mt = 0; mt < 4; ++mt)
#pragma unroll
                for (int nt = 0; nt < 4; ++nt)
                    acc[mt][nt] = __builtin_amdgcn_mfma_f32_16x16x32_bf16(
                        af[mt], bfr[nt], acc[mt][nt], 0, 0, 0);
        }
    }

#pragma unroll
    for (int nt = 0; nt < 4; ++nt) {
        int n = bn0 + wn + nt * 16 + l15;
        float bv = bias[n];
#pragma unroll
        for (int mt = 0; mt < 4; ++mt) {
            int m = bm0 + wm + mt * 16 + l4 * 4;
            float* op = out + (size_t)m * N_DIM + n;
#pragma unroll
            for (int r = 0; r < 4; ++r)
                op[(size_t)r * N_DIM] = acc[mt][nt][r] + bv;
        }
    }
}

extern "C" void kernel_launch(void* const* d_in, const int* in_sizes, int n_in,
                              void* d_out, int out_size, void* d_ws, size_t ws_size,
                              hipStream_t stream) {
    const float* x    = (const float*)d_in[0];
    const float* kern = (const float*)d_in[1];
    const float* bias = (const float*)d_in[2];
    const float* amat = (const float*)d_in[3];
    const float* bmat = (const float*)d_in[4];
    float* out = (float*)d_out;
    const int M = in_sizes[0] / K_DIM;   // 32768

    float* blockmax = (float*)d_ws;                          // 256 floats
    __bf16* wt = (__bf16*)((char*)d_ws + 4096);
    const size_t need = 4096 + (size_t)N_DIM * K_DIM * sizeof(__bf16);
    (void)need;

    maxabs_kernel<<<256, 256, 0, stream>>>(kern, blockmax, K_DIM * N_DIM / 4);
    build_w_kernel<<<K_DIM * N_DIM / 256, 256, 0, stream>>>(kern, amat, bmat, blockmax, wt);

    // fast path needs M divisible by 256*8 (panel-swizzle bijectivity)
    if ((M % (BM2 * 8)) == 0) {
        gemm256_kernel<<<(M / BM2) * (N_DIM / BN2), 512, 0, stream>>>(x, wt, bias, out);
    } else {
        gemm_fb_kernel<<<(M / BM) * (N_DIM / BN), 256, 0, stream>>>(x, wt, bias, out);
    }
}